// Round 5
// baseline (188.570 us; speedup 1.0000x reference)
//
#include <hip/hip_runtime.h>
#include <stdint.h>

// Problem constants
#define B_ 16
#define C_ 512
#define T_ 4000
#define TPAD 4096   // hT rows padded per batch so tail N-tiles read in-bounds

typedef float f32x4 __attribute__((ext_vector_type(4)));
typedef float f32x16 __attribute__((ext_vector_type(16)));
typedef __bf16 bf16x8 __attribute__((ext_vector_type(8)));

// ---------- helpers ----------
__device__ inline unsigned short f2b(float f) {   // fp32 -> bf16 bits, RNE
  uint32_t u = __builtin_bit_cast(uint32_t, f);
  u = (u + 0x7fffu + ((u >> 16) & 1u)) >> 16;
  return (unsigned short)u;
}
__device__ inline float b2f(unsigned short h) {
  uint32_t u = ((uint32_t)h) << 16;
  return __builtin_bit_cast(float, u);
}
__device__ inline void gl_lds16(const void* g, void* s) {
  __builtin_amdgcn_global_load_lds(
      (const __attribute__((address_space(1))) uint32_t*)g,
      (__attribute__((address_space(3))) uint32_t*)s, 16, 0, 0);
}

// ws float layout: [0..15] sum, [16..31] sumsq, [32..47] mean, [48..63] rstd,
//                  [64..575] s1[o], [576..1087] s2[o]
// byte 8192  : Wp bf16 [512][512]  (pw * gln_gamma, row-major o,c)
// byte 1<<20 : hT bf16 [16][4096][512]  (t-major, c contiguous)

__global__ void k_init(float* wsf) {
  int i = threadIdx.x;
  if (i < 32) wsf[i] = 0.f;
}

// one block per output row o: W'[o,c] = pw*gamma (bf16), s1[o]=sum W', s2[o]=sum pw*beta
__global__ __launch_bounds__(64) void k_prepw(const float* __restrict__ pw,
                                              const float* __restrict__ gamma,
                                              const float* __restrict__ beta,
                                              unsigned short* __restrict__ Wp,
                                              float* __restrict__ wsf) {
  int o = blockIdx.x, l = threadIdx.x;
  float a1 = 0.f, a2 = 0.f;
  for (int j = 0; j < 8; ++j) {
    int c = j * 64 + l;
    float wv = pw[o * 512 + c];
    unsigned short wb = f2b(wv * gamma[c]);
    Wp[o * 512 + c] = wb;
    a1 += b2f(wb);              // consistent with bf16 weights used in GEMM
    a2 += wv * beta[c];
  }
  for (int s = 32; s > 0; s >>= 1) { a1 += __shfl_down(a1, s); a2 += __shfl_down(a2, s); }
  if (l == 0) { wsf[64 + o] = a1; wsf[576 + o] = a2; }
}

// fused ReLU+BN+dwconv3+PReLU; writes hT[b][t][c] bf16 (transposed) + stats.
__global__ __launch_bounds__(512) void k_front(const float* __restrict__ x,
    const float* __restrict__ bng, const float* __restrict__ bnb,
    const float* __restrict__ bnm, const float* __restrict__ bnv,
    const float* __restrict__ dw, const float* __restrict__ pa,
    unsigned short* __restrict__ hT, float* __restrict__ wsf) {
  __shared__ unsigned short hs[256 * 128] __attribute__((aligned(16)));  // 64 KB
  __shared__ float psc[128], pbi[128], pq0[128], pq1[128], pq2[128];
  __shared__ float partial[16];
  int tid = threadIdx.x;
  int l = tid & 63, w = tid >> 6;
  int tb = blockIdx.x;   // 16 t-tiles of 256
  int cb = blockIdx.y;   // 4 c-chunks of 128
  int b  = blockIdx.z;
  int t0 = tb * 256;
  if (tid < 128) {
    int c = cb * 128 + tid;
    float sc = bng[c] * rsqrtf(bnv[c] + 1e-5f);
    psc[tid] = sc;
    pbi[tid] = bnb[c] - bnm[c] * sc;
    pq0[tid] = dw[3 * c];
    pq1[tid] = dw[3 * c + 1];
    pq2[tid] = dw[3 * c + 2];
  }
  float alpha = pa[0];
  __syncthreads();

  int t = t0 + 4 * l;
  bool full = (t + 3 < T_);          // lanes are either fully valid or fully out
  bool has_l = (t0 > 0);
  bool has_r = (t0 + 256 < T_);
  float sum = 0.f, sq = 0.f;
  int cs_x = (l & 7) << 3;           // swizzle term (t>>2 == l for all 4 outputs)

#pragma unroll 2
  for (int i = 0; i < 16; ++i) {
    int cl = w * 16 + i;
    const float* xr = x + ((size_t)b * C_ + cb * 128 + cl) * T_;
    float sc = psc[cl], bi = pbi[cl];
    float w0 = pq0[cl], w1 = pq1[cl], w2 = pq2[cl];
    f32x4 u;
    if (full) {
      const f32x4 v = *(const f32x4*)(xr + t);
      u.x = fmaxf(v.x, 0.f) * sc + bi;
      u.y = fmaxf(v.y, 0.f) * sc + bi;
      u.z = fmaxf(v.z, 0.f) * sc + bi;
      u.w = fmaxf(v.w, 0.f) * sc + bi;
    } else {
      u = (f32x4){0.f, 0.f, 0.f, 0.f};
    }
    float el = has_l ? (fmaxf(xr[t0 - 1], 0.f) * sc + bi) : 0.f;   // uniform addr
    float er = has_r ? (fmaxf(xr[t0 + 256], 0.f) * sc + bi) : 0.f; // uniform addr
    float up = __shfl_up(u.w, 1);   if (l == 0)  up = el;
    float un = __shfl_down(u.x, 1); if (l == 63) un = er;
    float h[4];
    h[0] = w0 * up  + w1 * u.x + w2 * u.y;
    h[1] = w0 * u.x + w1 * u.y + w2 * u.z;
    h[2] = w0 * u.y + w1 * u.z + w2 * u.w;
    h[3] = w0 * u.z + w1 * u.w + w2 * un;
    int cs = cl ^ cs_x;
#pragma unroll
    for (int j = 0; j < 4; ++j) {
      float p = h[j] >= 0.f ? h[j] : alpha * h[j];
      if (!full) p = 0.f;            // t >= 4000 rows stay exactly zero
      sum += p; sq += p * p;
      hs[(4 * l + j) * 128 + cs] = f2b(p);
    }
  }

  for (int s = 32; s > 0; s >>= 1) { sum += __shfl_down(sum, s); sq += __shfl_down(sq, s); }
  if (l == 0) { partial[w] = sum; partial[8 + w] = sq; }
  __syncthreads();
  if (tid == 0) {
    float a = 0.f, c2 = 0.f;
    for (int k = 0; k < 8; ++k) { a += partial[k]; c2 += partial[8 + k]; }
    atomicAdd(&wsf[b], a);
    atomicAdd(&wsf[16 + b], c2);
  }

  // LDS tile -> global hT[b][t0+tl][cb*128 + g*8], un-swizzled, 16B/thread/pass
  unsigned short* dstb = hT + ((size_t)b * TPAD + t0) * 512 + cb * 128;
#pragma unroll
  for (int p = 0; p < 8; ++p) {
    int idx = p * 512 + tid;
    int tl = idx >> 4, g = idx & 15;
    int gs = g ^ ((tl >> 2) & 7);
    uint4 val = *(const uint4*)(hs + tl * 128 + gs * 8);
    *(uint4*)(dstb + (size_t)tl * 512 + g * 8) = val;
  }
}

__global__ void k_finalize(float* wsf) {
  int b = threadIdx.x;
  if (b < 16) {
    float n = (float)C_ * (float)T_;
    float mean = wsf[b] / n;
    float var = wsf[16 + b] / n - mean * mean;
    wsf[32 + b] = mean;
    wsf[48 + b] = rsqrtf(fmaxf(var, 0.f) + 1e-8f);
  }
}

// GEMM v4: barrier-free K-loop.
// Block = full M(512) x 64-t tile. B (hT tile, 64x512 bf16 = 64KB) staged to LDS
// ONCE (pre-swizzled source, slot^(t&31)); A (Wp) streamed from L2 directly to
// registers, manually double-buffered (even/odd bodies, static reg names).
// 8 waves x (64o x 64t) via mfma_32x32x16_bf16, acc 2x2xf32x16.
// No barriers and no LDS writes inside the K-loop; compiler schedules waits.
__global__ __launch_bounds__(512, 4) void k_gemm(const unsigned short* __restrict__ Wp,
    const unsigned short* __restrict__ hT, const float* __restrict__ x,
    const float* __restrict__ wsf, float* __restrict__ out) {
  __shared__ unsigned short Bs[64 * 512] __attribute__((aligned(16)));  // 64 KB
  int tid = threadIdx.x;
  int l = tid & 63, w = tid >> 6;
  int nb = blockIdx.x, b = blockIdx.y;
  const unsigned short* hTt = hT + ((size_t)b * TPAD + nb * 64) * 512;

  // stage B once: LDS[t][slot'] = global[t][slot' ^ (t&31)]  (16B slots, linear dest)
#pragma unroll
  for (int r = 0; r < 8; ++r) {
    int u = r * 512 + tid;
    int row = u >> 6, slot = u & 63;
    gl_lds16(hTt + row * 512 + ((slot ^ (row & 31)) << 3), Bs + u * 8);
  }
  asm volatile("s_waitcnt vmcnt(0)" ::: "memory");
  __syncthreads();

  int o0 = w * 64;
  int lr = l & 31, lh = l >> 5;
  // A source base: row o0+fm*32+lr, k = kt*32 + ks*16 + lh*8
  const unsigned short* wpb = Wp + (size_t)(o0 + lr) * 512 + lh * 8;
  // B read: t_r = fn*32+lr, raw slot = kt*4+ks*2+lh, stored at raw^lr
  const unsigned short* bs0 = Bs + lr * 512;

  f32x16 acc[2][2] = {};
  bf16x8 A0[2][2], A1[2][2];
#pragma unroll
  for (int fm = 0; fm < 2; ++fm)
#pragma unroll
    for (int ks = 0; ks < 2; ++ks)
      A0[fm][ks] = *(const bf16x8*)(wpb + fm * 32 * 512 + ks * 16);

#pragma unroll 1
  for (int kt = 0; kt < 16; kt += 2) {
    // ---- even body: compute with A0, prefetch kt+1 -> A1 ----
#pragma unroll
    for (int fm = 0; fm < 2; ++fm)
#pragma unroll
      for (int ks = 0; ks < 2; ++ks)
        A1[fm][ks] = *(const bf16x8*)(wpb + fm * 32 * 512 + (kt + 1) * 32 + ks * 16);
    {
      bf16x8 bv[2][2];
#pragma unroll
      for (int fn = 0; fn < 2; ++fn)
#pragma unroll
        for (int ks = 0; ks < 2; ++ks) {
          int slot = (kt * 4 + ks * 2 + lh) ^ lr;
          bv[fn][ks] = *(const bf16x8*)(bs0 + fn * 32 * 512 + slot * 8);
        }
#pragma unroll
      for (int ks = 0; ks < 2; ++ks)
#pragma unroll
        for (int fm = 0; fm < 2; ++fm)
#pragma unroll
          for (int fn = 0; fn < 2; ++fn)
            acc[fm][fn] = __builtin_amdgcn_mfma_f32_32x32x16_bf16(
                A0[fm][ks], bv[fn][ks], acc[fm][fn], 0, 0, 0);
    }
    // ---- odd body: compute with A1, prefetch kt+2 -> A0 ----
    if (kt + 2 < 16) {
#pragma unroll
      for (int fm = 0; fm < 2; ++fm)
#pragma unroll
        for (int ks = 0; ks < 2; ++ks)
          A0[fm][ks] = *(const bf16x8*)(wpb + fm * 32 * 512 + (kt + 2) * 32 + ks * 16);
    }
    {
      bf16x8 bv[2][2];
#pragma unroll
      for (int fn = 0; fn < 2; ++fn)
#pragma unroll
        for (int ks = 0; ks < 2; ++ks) {
          int slot = ((kt + 1) * 4 + ks * 2 + lh) ^ lr;
          bv[fn][ks] = *(const bf16x8*)(bs0 + fn * 32 * 512 + slot * 8);
        }
#pragma unroll
      for (int ks = 0; ks < 2; ++ks)
#pragma unroll
        for (int fm = 0; fm < 2; ++fm)
#pragma unroll
          for (int fn = 0; fn < 2; ++fn)
            acc[fm][fn] = __builtin_amdgcn_mfma_f32_32x32x16_bf16(
                A1[fm][ks], bv[fn][ks], acc[fm][fn], 0, 0, 0);
    }
  }

  // epilogue: out[b,o,t] = rstd*acc + (s2[o]-mean*rstd*s1[o]) + x[b,o,t]
  float mean = wsf[32 + b], rstd = wsf[48 + b];
  float mr = mean * rstd;
#pragma unroll
  for (int fm = 0; fm < 2; ++fm) {
#pragma unroll
    for (int fn = 0; fn < 2; ++fn) {
      int t = nb * 64 + fn * 32 + lr;
      if (t < T_) {
#pragma unroll
        for (int reg = 0; reg < 16; ++reg) {
          int o = o0 + fm * 32 + (reg & 3) + ((reg >> 2) << 3) + (lh << 2);
          float bias = wsf[576 + o] - mr * wsf[64 + o];
          size_t idx = ((size_t)b * C_ + o) * T_ + t;
          out[idx] = rstd * acc[fm][fn][reg] + bias + x[idx];
        }
      }
    }
  }
}

extern "C" void kernel_launch(void* const* d_in, const int* in_sizes, int n_in,
                              void* d_out, int out_size, void* d_ws, size_t ws_size,
                              hipStream_t stream) {
  const float* x   = (const float*)d_in[0];
  const float* bng = (const float*)d_in[1];
  const float* bnb = (const float*)d_in[2];
  const float* bnm = (const float*)d_in[3];
  const float* bnv = (const float*)d_in[4];
  const float* dw  = (const float*)d_in[5];
  const float* pa  = (const float*)d_in[6];
  const float* gg  = (const float*)d_in[7];
  const float* gb  = (const float*)d_in[8];
  const float* pw  = (const float*)d_in[9];
  float* out = (float*)d_out;
  float* wsf = (float*)d_ws;
  unsigned short* Wp = (unsigned short*)((char*)d_ws + 8192);
  unsigned short* hT = (unsigned short*)((char*)d_ws + (1 << 20));

  k_init<<<dim3(1), dim3(64), 0, stream>>>(wsf);
  k_prepw<<<dim3(512), dim3(64), 0, stream>>>(pw, gg, gb, Wp, wsf);
  k_front<<<dim3(16, 4, 16), dim3(512), 0, stream>>>(x, bng, bnb, bnm, bnv, dw, pa, hT, wsf);
  k_finalize<<<dim3(1), dim3(64), 0, stream>>>(wsf);
  k_gemm<<<dim3(64, 16), dim3(512), 0, stream>>>(Wp, hT, x, wsf, out);
}